// Round 23
// baseline (234.715 us; speedup 1.0000x reference)
//
#include <hip/hip_runtime.h>
#include <hip/hip_bf16.h>
#include <math.h>

#define B_TOK 8192
#define DIM   512
#define HID   2048
#define NE    8

#define BN 128
#define MAX_TILES 136     // 128-row tiles: 17408 slots max
#define MAX_TILES64 272   // 64-row tiles over the same slot space

typedef __attribute__((ext_vector_type(4))) float f32x4;
typedef __attribute__((ext_vector_type(8))) short short8;

typedef __attribute__((address_space(3))) unsigned int lds_u32_t;
typedef __attribute__((address_space(1))) unsigned int glob_u32_t;

__device__ __forceinline__ unsigned short f2bf(float f) {
  unsigned u = __builtin_bit_cast(unsigned, f);
  unsigned r = 0x7FFFu + ((u >> 16) & 1u);
  return (unsigned short)((u + r) >> 16);
}

__device__ __forceinline__ float bf2f(unsigned short u) {
  unsigned v = (unsigned)u << 16;
  return __builtin_bit_cast(float, v);
}

__device__ __forceinline__ void gld_lds16(const unsigned short* g, unsigned short* l) {
  __builtin_amdgcn_global_load_lds((const glob_u32_t*)g, (lds_u32_t*)l, 16, 0, 0);
}

// fast gelu (tanh form): x * t/(t+1), t = exp(1.59577*(x + 0.044715 x^3))
__device__ __forceinline__ float gelu_fast(float x) {
  float u = x * (1.5957691216f + 0.0713548162f * x * x);
  float t = __expf(u);
  return x * t * __builtin_amdgcn_rcpf(t + 1.0f);
}

// ---------------- merged transpose: [E][R][C] fp32 -> [E][C][R] bf16 for W1 and W2 ----------------
__global__ __launch_bounds__(256) void k_transpose2(const float* __restrict__ W1,
                                                    const float* __restrict__ W2,
                                                    unsigned short* __restrict__ w1t,
                                                    unsigned short* __restrict__ w2t) {
  __shared__ float tile[32][33];
  int z = blockIdx.z;
  const float* ine;
  unsigned short* oute;
  int R, C;
  if (z < NE) { ine = W1 + (size_t)z * DIM * HID; oute = w1t + (size_t)z * DIM * HID; R = DIM; C = HID; }
  else        { ine = W2 + (size_t)(z - NE) * HID * DIM; oute = w2t + (size_t)(z - NE) * HID * DIM; R = HID; C = DIM; }
  int Ct = C >> 5;
  int r0 = (blockIdx.x / Ct) * 32, c0 = (blockIdx.x % Ct) * 32;
  int tc = threadIdx.x & 31, tr = threadIdx.x >> 5;
#pragma unroll
  for (int i = 0; i < 4; ++i) {
    int r = tr + i * 8;
    tile[r][tc] = ine[(size_t)(r0 + r) * C + (c0 + tc)];
  }
  __syncthreads();
#pragma unroll
  for (int i = 0; i < 4; ++i) {
    int r = tr + i * 8;
    oute[(size_t)(c0 + r) * R + (r0 + tc)] = f2bf(tile[tc][r]);
  }
}

// ---------------- gating (+ fused x->bf16), 8-way d-split, block-aggregated atomics ----------------
__global__ __launch_bounds__(256) void k_gate(const float* __restrict__ x,
                                              const float* __restrict__ Wg,
                                              const float* __restrict__ bg,
                                              float* __restrict__ topi,
                                              unsigned short* __restrict__ xbf,
                                              int* __restrict__ pairTok,
                                              int* __restrict__ tokEP,
                                              float* __restrict__ tokW,
                                              int* __restrict__ cnt) {
  __shared__ float wgs[DIM * NE + 28];    // sw(i) = i + (i>>9)*4
  __shared__ double partial[32][8][9];    // padded
  __shared__ double bgs[NE];
  __shared__ int lcnt[NE], lbase[NE];
  int t = threadIdx.x;
  if (t < NE) { bgs[t] = (double)bg[t]; lcnt[t] = 0; }
  for (int i = t; i < DIM * NE; i += 256) wgs[i + ((i >> 9) << 2)] = Wg[i];
  __syncthreads();

  int tokLocal = t >> 3;                  // 0..31
  int part = t & 7;                       // 0..7
  int token = blockIdx.x * 32 + tokLocal;
  size_t xoff = (size_t)token * DIM + part * 64;
  const float4* xr = (const float4*)(x + xoff);
  ushort4* xw = (ushort4*)(xbf + xoff);

  double acc[NE];
#pragma unroll
  for (int e = 0; e < NE; ++e) acc[e] = 0.0;

#pragma unroll
  for (int j = 0; j < 16; ++j) {          // 16 x float4 = 64 d
    float4 xv4 = xr[j];
    ushort4 o;
    o.x = f2bf(xv4.x); o.y = f2bf(xv4.y); o.z = f2bf(xv4.z); o.w = f2bf(xv4.w);
    xw[j] = o;
    const float* wb = &wgs[part * 516 + (j * 4) * 8];
#pragma unroll
    for (int k = 0; k < 4; ++k) {
      double xv = (double)((const float*)&xv4)[k];
#pragma unroll
      for (int e = 0; e < NE; ++e) acc[e] += xv * (double)wb[k * 8 + e];
    }
  }

#pragma unroll
  for (int e = 0; e < NE; ++e) partial[tokLocal][part][e] = acc[e];
  __syncthreads();

  int i0 = 0, i1 = 0, ls0 = 0, ls1 = 0;
  float w0 = 0.f, w1 = 0.f;
  if (part == 0) {
    double lg[NE];
#pragma unroll
    for (int e = 0; e < NE; ++e) {
      double s = bgs[e];
#pragma unroll
      for (int p = 0; p < 8; ++p) s += partial[tokLocal][p][e];
      lg[e] = s;
    }
    for (int e = 1; e < NE; ++e) if (lg[e] > lg[i0]) i0 = e;
    i1 = (i0 == 0) ? 1 : 0;
    for (int e = i1 + 1; e < NE; ++e) if (e != i0 && lg[e] > lg[i1]) i1 = e;
    double ex = exp(lg[i1] - lg[i0]);
    w0 = (float)(1.0 / (1.0 + ex));
    w1 = (float)(ex / (1.0 + ex));
    topi[token * 2 + 0] = (float)i0;
    topi[token * 2 + 1] = (float)i1;
    ls0 = atomicAdd(&lcnt[i0], 1);        // LDS atomics: 32 threads, cheap
    ls1 = atomicAdd(&lcnt[i1], 1);
  }
  __syncthreads();
  if (t < NE) lbase[t] = atomicAdd(&cnt[t], lcnt[t]);   // 8 global atomics/block
  __syncthreads();
  if (part == 0) {
    int s0 = lbase[i0] + ls0;
    int s1 = lbase[i1] + ls1;
    pairTok[i0 * B_TOK + s0] = token;
    pairTok[i1 * B_TOK + s1] = token;
    tokEP[token * 2 + 0] = (i0 << 16) | s0;  tokW[token * 2 + 0] = w0;
    tokEP[token * 2 + 1] = (i1 << 16) | s1;  tokW[token * 2 + 1] = w1;
  }
}

// ---------------- schedule ----------------
__global__ __launch_bounds__(256) void k_schedule(const int* __restrict__ cnt,
                                                  int* __restrict__ numTiles,
                                                  int4* __restrict__ tileInfo,
                                                  int4* __restrict__ tileInfo64,
                                                  int* __restrict__ sBase,
                                                  int* __restrict__ pairTok) {
  __shared__ int sc[NE], spc[NE];
  int t = threadIdx.x;
  if (t == 0) {
    int off = 0, nt = 0, nt64 = 0;
    for (int e = 0; e < NE; ++e) {
      int c = cnt[e];
      sc[e] = c;
      int tl = (c + 127) >> 7;
      spc[e] = tl << 7;
      sBase[e] = off;
      for (int lt = 0; lt < tl; ++lt)
        tileInfo[nt++] = make_int4(e, e * B_TOK + lt * 128, off + lt * 128, 0);
      for (int lt = 0; lt < tl * 2; ++lt)
        tileInfo64[nt64++] = make_int4(e, off + lt * 64, 0, 0);
      off += tl << 7;
    }
    numTiles[0] = nt;
    numTiles[1] = nt64;
  }
  __syncthreads();
  for (int e = 0; e < NE; ++e)
    for (int i = sc[e] + t; i < spc[e]; i += 256)
      pairTok[e * B_TOK + i] = 0;
}

// ---------------- GEMM1: h = gelu(gather(x) @ W1[e] + b1[e]) -> bf16
//  128x128, BK=32, 2-buf dbuf, 512 threads / 8 waves (wave tile 64x32),
//  XCD swizzle, swapped-MFMA epilogue. launch_bounds(512,8): target 4 blocks/CU.
__global__ __launch_bounds__(512, 8) void k_gemm1(const unsigned short* __restrict__ xbf,
                                               const unsigned short* __restrict__ w1t,
                                               const float* __restrict__ b1,
                                               const int4* __restrict__ tileInfo,
                                               const int* __restrict__ numTiles,
                                               const int* __restrict__ pairTok,
                                               unsigned short* __restrict__ hbuf) {
  // 2176 blocks = 8 xcd x (17 tiles x 16 n-blocks)
  int L = blockIdx.y * 16 + blockIdx.x;
  int xcd = L & 7, o = L >> 3;
  int tile = xcd * 17 + (o >> 4);
  int n0 = (o & 15) * BN;
  if (tile >= numTiles[0]) return;
  int4 info = tileInfo[tile];
  int e = info.x, pairBase = info.y, slotBase = info.z;
  __shared__ unsigned short As[2][4096];   // [g<4][row<128][8]
  __shared__ unsigned short Bs[2][4096];
  __shared__ int toks[128];
  int t = threadIdx.x;
  if (t < 128) toks[t] = pairTok[pairBase + t];
  __syncthreads();
  int row = t & 127, g4 = t >> 7;
  const unsigned short* aSrc = xbf + (size_t)toks[row] * DIM + g4 * 8;
  const unsigned short* bSrc = w1t + ((size_t)e * HID + n0 + row) * DIM + g4 * 8;
  int wv = t >> 6, lane = t & 63;
  int g = lane >> 4, r16 = lane & 15;
  int wr = (wv >> 2) * 64, wc = (wv & 3) * 32;   // 2M x 4N waves, wave tile 64x32
  f32x4 acc[4][2];
#pragma unroll
  for (int mi = 0; mi < 4; ++mi)
#pragma unroll
    for (int ni = 0; ni < 2; ++ni) acc[mi][ni] = (f32x4){0.f, 0.f, 0.f, 0.f};

#define G1_STAGE(buf, k0)                          \
  {                                                \
    gld_lds16(aSrc + (k0), &As[buf][wv * 512]);    \
    gld_lds16(bSrc + (k0), &Bs[buf][wv * 512]);    \
  }

  G1_STAGE(0, 0);
  __syncthreads();

  for (int ks = 0; ks < 16; ++ks) {
    int cur = ks & 1;
    if (ks < 15) G1_STAGE(cur ^ 1, (ks + 1) * 32);
    short8 am[4], bn[2];
#pragma unroll
    for (int mi = 0; mi < 4; ++mi)
      am[mi] = *(const short8*)&As[cur][((g * 128) + wr + mi * 16 + r16) * 8];
#pragma unroll
    for (int ni = 0; ni < 2; ++ni)
      bn[ni] = *(const short8*)&Bs[cur][((g * 128) + wc + ni * 16 + r16) * 8];
    // swapped operands: D^T fragment -> lane holds slot row (r16) x 4 consecutive cols
#pragma unroll
    for (int mi = 0; mi < 4; ++mi)
#pragma unroll
      for (int ni = 0; ni < 2; ++ni)
        acc[mi][ni] = __builtin_amdgcn_mfma_f32_16x16x32_bf16(bn[ni], am[mi], acc[mi][ni], 0, 0, 0);
    __syncthreads();
  }
#undef G1_STAGE

#pragma unroll
  for (int mi = 0; mi < 4; ++mi) {
    int srow = wr + mi * 16 + r16;
    size_t base = (size_t)(slotBase + srow) * HID;
#pragma unroll
    for (int ni = 0; ni < 2; ++ni) {
      int col0 = n0 + wc + ni * 16 + g * 4;
      float4 b4 = *(const float4*)&b1[e * HID + col0];
      unsigned h0 = f2bf(gelu_fast(acc[mi][ni][0] + b4.x));
      unsigned h1 = f2bf(gelu_fast(acc[mi][ni][1] + b4.y));
      unsigned h2 = f2bf(gelu_fast(acc[mi][ni][2] + b4.z));
      unsigned h3 = f2bf(gelu_fast(acc[mi][ni][3] + b4.w));
      uint2 pk;
      pk.x = h0 | (h1 << 16);
      pk.y = h2 | (h3 << 16);
      *(uint2*)&hbuf[base + col0] = pk;
    }
  }
}

// ---------------- GEMM2: ybuf[slot] = h[slot] @ W2[e] + b2[e]
//  64x64x64, XOR-swizzled LDS, 2-phase dbuf, XCD swizzle, swapped-MFMA epilogue.
//  launch_bounds(256,8): target 8 blocks/CU.
__global__ __launch_bounds__(256, 8) void k_gemm2(const unsigned short* __restrict__ hbuf,
                                               const unsigned short* __restrict__ w2t,
                                               const float* __restrict__ b2,
                                               const int4* __restrict__ tileInfo64,
                                               const int* __restrict__ numTiles,
                                               unsigned short* __restrict__ ybuf) {
  // 2176 blocks = 8 xcd x (34 tiles x 8 n-blocks)
  int L = blockIdx.y * 8 + blockIdx.x;
  int xcd = L & 7, o = L >> 3;
  int tile = xcd * 34 + (o >> 3);
  int n0 = (o & 7) * 64;
  if (tile >= numTiles[1]) return;
  int4 info = tileInfo64[tile];
  int e = info.x, slotBase = info.y;
  __shared__ unsigned short As[2][4096];   // [row<64][granule<8][8], granule pre-swizzled by row&7
  __shared__ unsigned short Bs[2][4096];
  int t = threadIdx.x;
  int wv = t >> 6, lane = t & 63;

  int sg = t & 7, srow = t >> 3;
  int sj = sg ^ (srow & 7);
  const unsigned short* aSrc0 = hbuf + (size_t)(slotBase + srow) * HID + sj * 8;
  const unsigned short* aSrc1 = hbuf + (size_t)(slotBase + srow + 32) * HID + sj * 8;
  const unsigned short* bSrc0 = w2t + ((size_t)e * DIM + n0 + srow) * HID + sj * 8;
  const unsigned short* bSrc1 = w2t + ((size_t)e * DIM + n0 + srow + 32) * HID + sj * 8;

  int g16 = lane >> 4, r16 = lane & 15;
  int wr = (wv >> 1) * 32, wc = (wv & 1) * 32;
  f32x4 acc[2][2];
#pragma unroll
  for (int mi = 0; mi < 2; ++mi)
#pragma unroll
    for (int ni = 0; ni < 2; ++ni) acc[mi][ni] = (f32x4){0.f, 0.f, 0.f, 0.f};

  gld_lds16(aSrc0, &As[0][wv * 512]);
  gld_lds16(aSrc1, &As[0][2048 + wv * 512]);
  gld_lds16(bSrc0, &Bs[0][wv * 512]);
  gld_lds16(bSrc1, &Bs[0][2048 + wv * 512]);
  __syncthreads();

  for (int ks = 0; ks < 32; ++ks) {
    int cur = ks & 1;
    if (ks < 31) {
      int nb = cur ^ 1;
      int k0n = (ks + 1) * 64;
      gld_lds16(aSrc0 + k0n, &As[nb][wv * 512]);
      gld_lds16(aSrc1 + k0n, &As[nb][2048 + wv * 512]);
      gld_lds16(bSrc0 + k0n, &Bs[nb][wv * 512]);
      gld_lds16(bSrc1 + k0n, &Bs[nb][2048 + wv * 512]);
    }
    short8 am[2][2], bn[2][2];
#pragma unroll
    for (int mi = 0; mi < 2; ++mi) {
      int rrow = wr + mi * 16 + r16;
#pragma unroll
      for (int kk = 0; kk < 2; ++kk) {
        int j = (kk * 4 + g16) ^ (rrow & 7);
        am[mi][kk] = *(const short8*)&As[cur][rrow * 64 + j * 8];
      }
    }
#pragma unroll
    for (int ni = 0; ni < 2; ++ni) {
      int rrow = wc + ni * 16 + r16;
#pragma unroll
      for (int kk = 0; kk < 2; ++kk) {
        int j = (kk * 4 + g16) ^ (rrow & 7);
        bn[ni][kk] = *(const short8*)&Bs[cur][rrow * 64 + j * 8];
      }
    }
    // swapped operands: lane holds slot row (r16) x 4 consecutive cols (g16*4+r)
#pragma unroll
    for (int mi = 0; mi < 2; ++mi)
#pragma unroll
      for (int ni = 0; ni < 2; ++ni)
#pragma unroll
        for (int kk = 0; kk < 2; ++kk)
          acc[mi][ni] = __builtin_amdgcn_mfma_f32_16x16x32_bf16(bn[ni][kk], am[mi][kk], acc[mi][ni], 0, 0, 0);
    __syncthreads();
  }

#pragma unroll
  for (int mi = 0; mi < 2; ++mi) {
    int srow2 = wr + mi * 16 + r16;
    size_t base = (size_t)(slotBase + srow2) * DIM;
#pragma unroll
    for (int ni = 0; ni < 2; ++ni) {
      int col0 = n0 + wc + ni * 16 + g16 * 4;
      float4 b4 = *(const float4*)&b2[e * DIM + col0];
      unsigned y0 = f2bf(acc[mi][ni][0] + b4.x);
      unsigned y1 = f2bf(acc[mi][ni][1] + b4.y);
      unsigned y2 = f2bf(acc[mi][ni][2] + b4.z);
      unsigned y3 = f2bf(acc[mi][ni][3] + b4.w);
      uint2 pk;
      pk.x = y0 | (y1 << 16);
      pk.y = y2 | (y3 << 16);
      *(uint2*)&ybuf[base + col0] = pk;
    }
  }
}

// ---------------- combine: out[token] = w0*y[slot0] + w1*y[slot1] ----------------
__global__ __launch_bounds__(256) void k_combine(const unsigned short* __restrict__ ybuf,
                                                 const int* __restrict__ tokEP,
                                                 const float* __restrict__ tokW,
                                                 const int* __restrict__ sBase,
                                                 float* __restrict__ out) {
  int gid = blockIdx.x * 256 + threadIdx.x;   // B_TOK*DIM/4 threads
  int token = gid >> 7;
  int c4 = (gid & 127) * 4;
  int ep0 = tokEP[token * 2], ep1 = tokEP[token * 2 + 1];
  float w0 = tokW[token * 2], w1 = tokW[token * 2 + 1];
  size_t s0 = (size_t)(sBase[ep0 >> 16] + (ep0 & 0xFFFF));
  size_t s1 = (size_t)(sBase[ep1 >> 16] + (ep1 & 0xFFFF));
  ushort4 a = *(const ushort4*)&ybuf[s0 * DIM + c4];
  ushort4 b = *(const ushort4*)&ybuf[s1 * DIM + c4];
  float4 o;
  o.x = w0 * bf2f(a.x) + w1 * bf2f(b.x);
  o.y = w0 * bf2f(a.y) + w1 * bf2f(b.y);
  o.z = w0 * bf2f(a.z) + w1 * bf2f(b.z);
  o.w = w0 * bf2f(a.w) + w1 * bf2f(b.w);
  ((float4*)out)[gid] = o;
}

extern "C" void kernel_launch(void* const* d_in, const int* in_sizes, int n_in,
                              void* d_out, int out_size, void* d_ws, size_t ws_size,
                              hipStream_t stream) {
  (void)in_sizes; (void)n_in; (void)out_size; (void)ws_size;
  const float* x  = (const float*)d_in[0];
  const float* Wg = (const float*)d_in[1];
  const float* bg = (const float*)d_in[2];
  const float* W1 = (const float*)d_in[3];
  const float* b1 = (const float*)d_in[4];
  const float* W2 = (const float*)d_in[5];
  const float* b2 = (const float*)d_in[6];
  float* out  = (float*)d_out;
  float* topi = out + (size_t)B_TOK * DIM;

  char* ws = (char*)d_ws;
  int*  cnt        = (int*)(ws + 0);                  // 32 B
  int*  numTiles   = (int*)(ws + 64);                 // 2 ints
  int*  sBase      = (int*)(ws + 128);                // 8 ints
  int4* tileInfo64 = (int4*)(ws + 256);               // 272*16 B
  int4* tileInfo   = (int4*)(ws + 8192);              // 136*16 B
  int*  pairTok    = (int*)(ws + 16384);              // 256 KiB
  int*  tokEP      = (int*)(ws + 16384 + 262144);     // 64 KiB
  float* tokW      = (float*)(ws + 16384 + 262144 + 65536); // 64 KiB
  unsigned short* ybuf = (unsigned short*)(ws + (1u << 20));  // 17.8 MiB, overlays xbf+w1t (dead after gemm1)
  unsigned short* xbf  = (unsigned short*)(ws + (1u << 20));
  unsigned short* w1t  = (unsigned short*)(ws + (1u << 20) + 8388608);
  unsigned short* w2t  = (unsigned short*)(ws + (1u << 20) + 8388608 + 16777216);
  unsigned short* hbuf = (unsigned short*)(ws + (1u << 20) + 8388608 + 16777216 + 16777216);

  hipMemsetAsync(cnt, 0, 64, stream);

  k_transpose2<<<dim3(1024, 1, 16), 256, 0, stream>>>(W1, W2, w1t, w2t);
  k_gate<<<dim3(B_TOK / 32), 256, 0, stream>>>(x, Wg, bg, topi, xbf, pairTok, tokEP, tokW, cnt);
  k_schedule<<<dim3(1), 256, 0, stream>>>(cnt, numTiles, tileInfo, tileInfo64, sBase, pairTok);
  k_gemm1<<<dim3(16, MAX_TILES), 512, 0, stream>>>(xbf, w1t, b1, tileInfo, numTiles, pairTok, hbuf);
  k_gemm2<<<dim3(8, MAX_TILES64), 256, 0, stream>>>(hbuf, w2t, b2, tileInfo64, numTiles, ybuf);
  k_combine<<<dim3((B_TOK * DIM) / 1024), 256, 0, stream>>>(ybuf, tokEP, tokW, sBase, out);
}

// Round 26
// 223.942 us; speedup vs baseline: 1.0481x; 1.0481x over previous
//
#include <hip/hip_runtime.h>
#include <hip/hip_bf16.h>
#include <math.h>

#define B_TOK 8192
#define DIM   512
#define HID   2048
#define NE    8

#define BN 128
#define MAX_TILES 136     // 128-row tiles: 17408 slots max
#define MAX_TILES64 272   // 64-row tiles over the same slot space

typedef __attribute__((ext_vector_type(4))) float f32x4;
typedef __attribute__((ext_vector_type(8))) short short8;

typedef __attribute__((address_space(3))) unsigned int lds_u32_t;
typedef __attribute__((address_space(1))) unsigned int glob_u32_t;

__device__ __forceinline__ unsigned short f2bf(float f) {
  unsigned u = __builtin_bit_cast(unsigned, f);
  unsigned r = 0x7FFFu + ((u >> 16) & 1u);
  return (unsigned short)((u + r) >> 16);
}

__device__ __forceinline__ float bf2f(unsigned short u) {
  unsigned v = (unsigned)u << 16;
  return __builtin_bit_cast(float, v);
}

__device__ __forceinline__ void gld_lds16(const unsigned short* g, unsigned short* l) {
  __builtin_amdgcn_global_load_lds((const glob_u32_t*)g, (lds_u32_t*)l, 16, 0, 0);
}

// fast gelu (tanh form): x * t/(t+1), t = exp(1.59577*(x + 0.044715 x^3))
__device__ __forceinline__ float gelu_fast(float x) {
  float u = x * (1.5957691216f + 0.0713548162f * x * x);
  float t = __expf(u);
  return x * t * __builtin_amdgcn_rcpf(t + 1.0f);
}

// ---------------- merged transpose: [E][R][C] fp32 -> [E][C][R] bf16 for W1 and W2 ----------------
__global__ __launch_bounds__(256) void k_transpose2(const float* __restrict__ W1,
                                                    const float* __restrict__ W2,
                                                    unsigned short* __restrict__ w1t,
                                                    unsigned short* __restrict__ w2t) {
  __shared__ float tile[32][33];
  int z = blockIdx.z;
  const float* ine;
  unsigned short* oute;
  int R, C;
  if (z < NE) { ine = W1 + (size_t)z * DIM * HID; oute = w1t + (size_t)z * DIM * HID; R = DIM; C = HID; }
  else        { ine = W2 + (size_t)(z - NE) * HID * DIM; oute = w2t + (size_t)(z - NE) * HID * DIM; R = HID; C = DIM; }
  int Ct = C >> 5;
  int r0 = (blockIdx.x / Ct) * 32, c0 = (blockIdx.x % Ct) * 32;
  int tc = threadIdx.x & 31, tr = threadIdx.x >> 5;
#pragma unroll
  for (int i = 0; i < 4; ++i) {
    int r = tr + i * 8;
    tile[r][tc] = ine[(size_t)(r0 + r) * C + (c0 + tc)];
  }
  __syncthreads();
#pragma unroll
  for (int i = 0; i < 4; ++i) {
    int r = tr + i * 8;
    oute[(size_t)(c0 + r) * R + (r0 + tc)] = f2bf(tile[tc][r]);
  }
}

// ---------------- gating (+ fused x->bf16), 8-way d-split, block-aggregated atomics ----------------
__global__ __launch_bounds__(256) void k_gate(const float* __restrict__ x,
                                              const float* __restrict__ Wg,
                                              const float* __restrict__ bg,
                                              float* __restrict__ topi,
                                              unsigned short* __restrict__ xbf,
                                              int* __restrict__ pairTok,
                                              int* __restrict__ tokEP,
                                              float* __restrict__ tokW,
                                              int* __restrict__ cnt) {
  __shared__ float wgs[DIM * NE + 28];    // sw(i) = i + (i>>9)*4
  __shared__ double partial[32][8][9];    // padded
  __shared__ double bgs[NE];
  __shared__ int lcnt[NE], lbase[NE];
  int t = threadIdx.x;
  if (t < NE) { bgs[t] = (double)bg[t]; lcnt[t] = 0; }
  for (int i = t; i < DIM * NE; i += 256) wgs[i + ((i >> 9) << 2)] = Wg[i];
  __syncthreads();

  int tokLocal = t >> 3;                  // 0..31
  int part = t & 7;                       // 0..7
  int token = blockIdx.x * 32 + tokLocal;
  size_t xoff = (size_t)token * DIM + part * 64;
  const float4* xr = (const float4*)(x + xoff);
  ushort4* xw = (ushort4*)(xbf + xoff);

  double acc[NE];
#pragma unroll
  for (int e = 0; e < NE; ++e) acc[e] = 0.0;

#pragma unroll
  for (int j = 0; j < 16; ++j) {          // 16 x float4 = 64 d
    float4 xv4 = xr[j];
    ushort4 o;
    o.x = f2bf(xv4.x); o.y = f2bf(xv4.y); o.z = f2bf(xv4.z); o.w = f2bf(xv4.w);
    xw[j] = o;
    const float* wb = &wgs[part * 516 + (j * 4) * 8];
#pragma unroll
    for (int k = 0; k < 4; ++k) {
      double xv = (double)((const float*)&xv4)[k];
#pragma unroll
      for (int e = 0; e < NE; ++e) acc[e] += xv * (double)wb[k * 8 + e];
    }
  }

#pragma unroll
  for (int e = 0; e < NE; ++e) partial[tokLocal][part][e] = acc[e];
  __syncthreads();

  int i0 = 0, i1 = 0, ls0 = 0, ls1 = 0;
  float w0 = 0.f, w1 = 0.f;
  if (part == 0) {
    double lg[NE];
#pragma unroll
    for (int e = 0; e < NE; ++e) {
      double s = bgs[e];
#pragma unroll
      for (int p = 0; p < 8; ++p) s += partial[tokLocal][p][e];
      lg[e] = s;
    }
    for (int e = 1; e < NE; ++e) if (lg[e] > lg[i0]) i0 = e;
    i1 = (i0 == 0) ? 1 : 0;
    for (int e = i1 + 1; e < NE; ++e) if (e != i0 && lg[e] > lg[i1]) i1 = e;
    double ex = exp(lg[i1] - lg[i0]);
    w0 = (float)(1.0 / (1.0 + ex));
    w1 = (float)(ex / (1.0 + ex));
    topi[token * 2 + 0] = (float)i0;
    topi[token * 2 + 1] = (float)i1;
    ls0 = atomicAdd(&lcnt[i0], 1);        // LDS atomics: 32 threads, cheap
    ls1 = atomicAdd(&lcnt[i1], 1);
  }
  __syncthreads();
  if (t < NE) lbase[t] = atomicAdd(&cnt[t], lcnt[t]);   // 8 global atomics/block
  __syncthreads();
  if (part == 0) {
    int s0 = lbase[i0] + ls0;
    int s1 = lbase[i1] + ls1;
    pairTok[i0 * B_TOK + s0] = token;
    pairTok[i1 * B_TOK + s1] = token;
    tokEP[token * 2 + 0] = (i0 << 16) | s0;  tokW[token * 2 + 0] = w0;
    tokEP[token * 2 + 1] = (i1 << 16) | s1;  tokW[token * 2 + 1] = w1;
  }
}

// ---------------- schedule ----------------
__global__ __launch_bounds__(256) void k_schedule(const int* __restrict__ cnt,
                                                  int* __restrict__ numTiles,
                                                  int4* __restrict__ tileInfo,
                                                  int4* __restrict__ tileInfo64,
                                                  int* __restrict__ sBase,
                                                  int* __restrict__ pairTok) {
  __shared__ int sc[NE], spc[NE];
  int t = threadIdx.x;
  if (t == 0) {
    int off = 0, nt = 0, nt64 = 0;
    for (int e = 0; e < NE; ++e) {
      int c = cnt[e];
      sc[e] = c;
      int tl = (c + 127) >> 7;
      spc[e] = tl << 7;
      sBase[e] = off;
      for (int lt = 0; lt < tl; ++lt)
        tileInfo[nt++] = make_int4(e, e * B_TOK + lt * 128, off + lt * 128, 0);
      for (int lt = 0; lt < tl * 2; ++lt)
        tileInfo64[nt64++] = make_int4(e, off + lt * 64, 0, 0);
      off += tl << 7;
    }
    numTiles[0] = nt;
    numTiles[1] = nt64;
  }
  __syncthreads();
  for (int e = 0; e < NE; ++e)
    for (int i = sc[e] + t; i < spc[e]; i += 256)
      pairTok[e * B_TOK + i] = 0;
}

// ---------------- GEMM1: h = gelu(gather(x) @ W1[e] + b1[e]) -> bf16
//  128x128, BK=32, 2-buf dbuf, 512 threads / 8 waves (wave tile 64x32),
//  XCD swizzle, swapped-MFMA epilogue. launch_bounds(512,6): 3 blocks/CU, no VGPR cap (85>=40).
__global__ __launch_bounds__(512, 6) void k_gemm1(const unsigned short* __restrict__ xbf,
                                               const unsigned short* __restrict__ w1t,
                                               const float* __restrict__ b1,
                                               const int4* __restrict__ tileInfo,
                                               const int* __restrict__ numTiles,
                                               const int* __restrict__ pairTok,
                                               unsigned short* __restrict__ hbuf) {
  // 2176 blocks = 8 xcd x (17 tiles x 16 n-blocks)
  int L = blockIdx.y * 16 + blockIdx.x;
  int xcd = L & 7, o = L >> 3;
  int tile = xcd * 17 + (o >> 4);
  int n0 = (o & 15) * BN;
  if (tile >= numTiles[0]) return;
  int4 info = tileInfo[tile];
  int e = info.x, pairBase = info.y, slotBase = info.z;
  __shared__ unsigned short As[2][4096];   // [g<4][row<128][8]
  __shared__ unsigned short Bs[2][4096];
  __shared__ int toks[128];
  int t = threadIdx.x;
  if (t < 128) toks[t] = pairTok[pairBase + t];
  __syncthreads();
  int row = t & 127, g4 = t >> 7;
  const unsigned short* aSrc = xbf + (size_t)toks[row] * DIM + g4 * 8;
  const unsigned short* bSrc = w1t + ((size_t)e * HID + n0 + row) * DIM + g4 * 8;
  int wv = t >> 6, lane = t & 63;
  int g = lane >> 4, r16 = lane & 15;
  int wr = (wv >> 2) * 64, wc = (wv & 3) * 32;   // 2M x 4N waves, wave tile 64x32
  f32x4 acc[4][2];
#pragma unroll
  for (int mi = 0; mi < 4; ++mi)
#pragma unroll
    for (int ni = 0; ni < 2; ++ni) acc[mi][ni] = (f32x4){0.f, 0.f, 0.f, 0.f};

#define G1_STAGE(buf, k0)                          \
  {                                                \
    gld_lds16(aSrc + (k0), &As[buf][wv * 512]);    \
    gld_lds16(bSrc + (k0), &Bs[buf][wv * 512]);    \
  }

  G1_STAGE(0, 0);
  __syncthreads();

  for (int ks = 0; ks < 16; ++ks) {
    int cur = ks & 1;
    if (ks < 15) G1_STAGE(cur ^ 1, (ks + 1) * 32);
    short8 am[4], bn[2];
#pragma unroll
    for (int mi = 0; mi < 4; ++mi)
      am[mi] = *(const short8*)&As[cur][((g * 128) + wr + mi * 16 + r16) * 8];
#pragma unroll
    for (int ni = 0; ni < 2; ++ni)
      bn[ni] = *(const short8*)&Bs[cur][((g * 128) + wc + ni * 16 + r16) * 8];
    // swapped operands: D^T fragment -> lane holds slot row (r16) x 4 consecutive cols
#pragma unroll
    for (int mi = 0; mi < 4; ++mi)
#pragma unroll
      for (int ni = 0; ni < 2; ++ni)
        acc[mi][ni] = __builtin_amdgcn_mfma_f32_16x16x32_bf16(bn[ni], am[mi], acc[mi][ni], 0, 0, 0);
    __syncthreads();
  }
#undef G1_STAGE

#pragma unroll
  for (int mi = 0; mi < 4; ++mi) {
    int srow = wr + mi * 16 + r16;
    size_t base = (size_t)(slotBase + srow) * HID;
#pragma unroll
    for (int ni = 0; ni < 2; ++ni) {
      int col0 = n0 + wc + ni * 16 + g * 4;
      float4 b4 = *(const float4*)&b1[e * HID + col0];
      unsigned h0 = f2bf(gelu_fast(acc[mi][ni][0] + b4.x));
      unsigned h1 = f2bf(gelu_fast(acc[mi][ni][1] + b4.y));
      unsigned h2 = f2bf(gelu_fast(acc[mi][ni][2] + b4.z));
      unsigned h3 = f2bf(gelu_fast(acc[mi][ni][3] + b4.w));
      uint2 pk;
      pk.x = h0 | (h1 << 16);
      pk.y = h2 | (h3 << 16);
      *(uint2*)&hbuf[base + col0] = pk;
    }
  }
}

// ---------------- GEMM2: ybuf[slot] = h[slot] @ W2[e] + b2[e]
//  64x64x64, XOR-swizzled LDS, 2-phase dbuf, XCD swizzle, swapped-MFMA epilogue.
__global__ __launch_bounds__(256) void k_gemm2(const unsigned short* __restrict__ hbuf,
                                               const unsigned short* __restrict__ w2t,
                                               const float* __restrict__ b2,
                                               const int4* __restrict__ tileInfo64,
                                               const int* __restrict__ numTiles,
                                               unsigned short* __restrict__ ybuf) {
  // 2176 blocks = 8 xcd x (34 tiles x 8 n-blocks)
  int L = blockIdx.y * 8 + blockIdx.x;
  int xcd = L & 7, o = L >> 3;
  int tile = xcd * 34 + (o >> 3);
  int n0 = (o & 7) * 64;
  if (tile >= numTiles[1]) return;
  int4 info = tileInfo64[tile];
  int e = info.x, slotBase = info.y;
  __shared__ unsigned short As[2][4096];   // [row<64][granule<8][8], granule pre-swizzled by row&7
  __shared__ unsigned short Bs[2][4096];
  int t = threadIdx.x;
  int wv = t >> 6, lane = t & 63;

  int sg = t & 7, srow = t >> 3;
  int sj = sg ^ (srow & 7);
  const unsigned short* aSrc0 = hbuf + (size_t)(slotBase + srow) * HID + sj * 8;
  const unsigned short* aSrc1 = hbuf + (size_t)(slotBase + srow + 32) * HID + sj * 8;
  const unsigned short* bSrc0 = w2t + ((size_t)e * DIM + n0 + srow) * HID + sj * 8;
  const unsigned short* bSrc1 = w2t + ((size_t)e * DIM + n0 + srow + 32) * HID + sj * 8;

  int g16 = lane >> 4, r16 = lane & 15;
  int wr = (wv >> 1) * 32, wc = (wv & 1) * 32;
  f32x4 acc[2][2];
#pragma unroll
  for (int mi = 0; mi < 2; ++mi)
#pragma unroll
    for (int ni = 0; ni < 2; ++ni) acc[mi][ni] = (f32x4){0.f, 0.f, 0.f, 0.f};

  gld_lds16(aSrc0, &As[0][wv * 512]);
  gld_lds16(aSrc1, &As[0][2048 + wv * 512]);
  gld_lds16(bSrc0, &Bs[0][wv * 512]);
  gld_lds16(bSrc1, &Bs[0][2048 + wv * 512]);
  __syncthreads();

  for (int ks = 0; ks < 32; ++ks) {
    int cur = ks & 1;
    if (ks < 31) {
      int nb = cur ^ 1;
      int k0n = (ks + 1) * 64;
      gld_lds16(aSrc0 + k0n, &As[nb][wv * 512]);
      gld_lds16(aSrc1 + k0n, &As[nb][2048 + wv * 512]);
      gld_lds16(bSrc0 + k0n, &Bs[nb][wv * 512]);
      gld_lds16(bSrc1 + k0n, &Bs[nb][2048 + wv * 512]);
    }
    short8 am[2][2], bn[2][2];
#pragma unroll
    for (int mi = 0; mi < 2; ++mi) {
      int rrow = wr + mi * 16 + r16;
#pragma unroll
      for (int kk = 0; kk < 2; ++kk) {
        int j = (kk * 4 + g16) ^ (rrow & 7);
        am[mi][kk] = *(const short8*)&As[cur][rrow * 64 + j * 8];
      }
    }
#pragma unroll
    for (int ni = 0; ni < 2; ++ni) {
      int rrow = wc + ni * 16 + r16;
#pragma unroll
      for (int kk = 0; kk < 2; ++kk) {
        int j = (kk * 4 + g16) ^ (rrow & 7);
        bn[ni][kk] = *(const short8*)&Bs[cur][rrow * 64 + j * 8];
      }
    }
    // swapped operands: lane holds slot row (r16) x 4 consecutive cols (g16*4+r)
#pragma unroll
    for (int mi = 0; mi < 2; ++mi)
#pragma unroll
      for (int ni = 0; ni < 2; ++ni)
#pragma unroll
        for (int kk = 0; kk < 2; ++kk)
          acc[mi][ni] = __builtin_amdgcn_mfma_f32_16x16x32_bf16(bn[ni][kk], am[mi][kk], acc[mi][ni], 0, 0, 0);
    __syncthreads();
  }

#pragma unroll
  for (int mi = 0; mi < 2; ++mi) {
    int srow2 = wr + mi * 16 + r16;
    size_t base = (size_t)(slotBase + srow2) * DIM;
#pragma unroll
    for (int ni = 0; ni < 2; ++ni) {
      int col0 = n0 + wc + ni * 16 + g16 * 4;
      float4 b4 = *(const float4*)&b2[e * DIM + col0];
      unsigned y0 = f2bf(acc[mi][ni][0] + b4.x);
      unsigned y1 = f2bf(acc[mi][ni][1] + b4.y);
      unsigned y2 = f2bf(acc[mi][ni][2] + b4.z);
      unsigned y3 = f2bf(acc[mi][ni][3] + b4.w);
      uint2 pk;
      pk.x = y0 | (y1 << 16);
      pk.y = y2 | (y3 << 16);
      *(uint2*)&ybuf[base + col0] = pk;
    }
  }
}

// ---------------- combine: out[token] = w0*y[slot0] + w1*y[slot1] ----------------
__global__ __launch_bounds__(256) void k_combine(const unsigned short* __restrict__ ybuf,
                                                 const int* __restrict__ tokEP,
                                                 const float* __restrict__ tokW,
                                                 const int* __restrict__ sBase,
                                                 float* __restrict__ out) {
  int gid = blockIdx.x * 256 + threadIdx.x;   // B_TOK*DIM/4 threads
  int token = gid >> 7;
  int c4 = (gid & 127) * 4;
  int ep0 = tokEP[token * 2], ep1 = tokEP[token * 2 + 1];
  float w0 = tokW[token * 2], w1 = tokW[token * 2 + 1];
  size_t s0 = (size_t)(sBase[ep0 >> 16] + (ep0 & 0xFFFF));
  size_t s1 = (size_t)(sBase[ep1 >> 16] + (ep1 & 0xFFFF));
  ushort4 a = *(const ushort4*)&ybuf[s0 * DIM + c4];
  ushort4 b = *(const ushort4*)&ybuf[s1 * DIM + c4];
  float4 o;
  o.x = w0 * bf2f(a.x) + w1 * bf2f(b.x);
  o.y = w0 * bf2f(a.y) + w1 * bf2f(b.y);
  o.z = w0 * bf2f(a.z) + w1 * bf2f(b.z);
  o.w = w0 * bf2f(a.w) + w1 * bf2f(b.w);
  ((float4*)out)[gid] = o;
}

extern "C" void kernel_launch(void* const* d_in, const int* in_sizes, int n_in,
                              void* d_out, int out_size, void* d_ws, size_t ws_size,
                              hipStream_t stream) {
  (void)in_sizes; (void)n_in; (void)out_size; (void)ws_size;
  const float* x  = (const float*)d_in[0];
  const float* Wg = (const float*)d_in[1];
  const float* bg = (const float*)d_in[2];
  const float* W1 = (const float*)d_in[3];
  const float* b1 = (const float*)d_in[4];
  const float* W2 = (const float*)d_in[5];
  const float* b2 = (const float*)d_in[6];
  float* out  = (float*)d_out;
  float* topi = out + (size_t)B_TOK * DIM;

  char* ws = (char*)d_ws;
  int*  cnt        = (int*)(ws + 0);                  // 32 B
  int*  numTiles   = (int*)(ws + 64);                 // 2 ints
  int*  sBase      = (int*)(ws + 128);                // 8 ints
  int4* tileInfo64 = (int4*)(ws + 256);               // 272*16 B
  int4* tileInfo   = (int4*)(ws + 8192);              // 136*16 B
  int*  pairTok    = (int*)(ws + 16384);              // 256 KiB
  int*  tokEP      = (int*)(ws + 16384 + 262144);     // 64 KiB
  float* tokW      = (float*)(ws + 16384 + 262144 + 65536); // 64 KiB
  unsigned short* ybuf = (unsigned short*)(ws + (1u << 20));  // 17.8 MiB, overlays xbf+w1t (dead after gemm1)
  unsigned short* xbf  = (unsigned short*)(ws + (1u << 20));
  unsigned short* w1t  = (unsigned short*)(ws + (1u << 20) + 8388608);
  unsigned short* w2t  = (unsigned short*)(ws + (1u << 20) + 8388608 + 16777216);
  unsigned short* hbuf = (unsigned short*)(ws + (1u << 20) + 8388608 + 16777216 + 16777216);

  hipMemsetAsync(cnt, 0, 64, stream);

  k_transpose2<<<dim3(1024, 1, 16), 256, 0, stream>>>(W1, W2, w1t, w2t);
  k_gate<<<dim3(B_TOK / 32), 256, 0, stream>>>(x, Wg, bg, topi, xbf, pairTok, tokEP, tokW, cnt);
  k_schedule<<<dim3(1), 256, 0, stream>>>(cnt, numTiles, tileInfo, tileInfo64, sBase, pairTok);
  k_gemm1<<<dim3(16, MAX_TILES), 512, 0, stream>>>(xbf, w1t, b1, tileInfo, numTiles, pairTok, hbuf);
  k_gemm2<<<dim3(8, MAX_TILES64), 256, 0, stream>>>(hbuf, w2t, b2, tileInfo64, numTiles, ybuf);
  k_combine<<<dim3((B_TOK * DIM) / 1024), 256, 0, stream>>>(ybuf, tokEP, tokW, sBase, out);
}

// Round 27
// 195.573 us; speedup vs baseline: 1.2001x; 1.1451x over previous
//
#include <hip/hip_runtime.h>
#include <hip/hip_bf16.h>
#include <math.h>

#define B_TOK 8192
#define DIM   512
#define HID   2048
#define NE    8

#define MAX_TILES 136     // 128-row tiles: 17408 slots max
#define MAX_TILES64 272   // 64-row tiles over the same slot space

typedef __attribute__((ext_vector_type(4))) float f32x4;
typedef __attribute__((ext_vector_type(8))) short short8;

typedef __attribute__((address_space(3))) unsigned int lds_u32_t;
typedef __attribute__((address_space(1))) unsigned int glob_u32_t;

__device__ __forceinline__ unsigned short f2bf(float f) {
  unsigned u = __builtin_bit_cast(unsigned, f);
  unsigned r = 0x7FFFu + ((u >> 16) & 1u);
  return (unsigned short)((u + r) >> 16);
}

__device__ __forceinline__ float bf2f(unsigned short u) {
  unsigned v = (unsigned)u << 16;
  return __builtin_bit_cast(float, v);
}

__device__ __forceinline__ void gld_lds16(const unsigned short* g, unsigned short* l) {
  __builtin_amdgcn_global_load_lds((const glob_u32_t*)g, (lds_u32_t*)l, 16, 0, 0);
}

// fast gelu (tanh form): x * t/(t+1), t = exp(1.59577*(x + 0.044715 x^3))
__device__ __forceinline__ float gelu_fast(float x) {
  float u = x * (1.5957691216f + 0.0713548162f * x * x);
  float t = __expf(u);
  return x * t * __builtin_amdgcn_rcpf(t + 1.0f);
}

// ---------------- merged transpose: [E][R][C] fp32 -> [E][C][R] bf16 for W1 and W2 ----------------
__global__ __launch_bounds__(256) void k_transpose2(const float* __restrict__ W1,
                                                    const float* __restrict__ W2,
                                                    unsigned short* __restrict__ w1t,
                                                    unsigned short* __restrict__ w2t) {
  __shared__ float tile[32][33];
  int z = blockIdx.z;
  const float* ine;
  unsigned short* oute;
  int R, C;
  if (z < NE) { ine = W1 + (size_t)z * DIM * HID; oute = w1t + (size_t)z * DIM * HID; R = DIM; C = HID; }
  else        { ine = W2 + (size_t)(z - NE) * HID * DIM; oute = w2t + (size_t)(z - NE) * HID * DIM; R = HID; C = DIM; }
  int Ct = C >> 5;
  int r0 = (blockIdx.x / Ct) * 32, c0 = (blockIdx.x % Ct) * 32;
  int tc = threadIdx.x & 31, tr = threadIdx.x >> 5;
#pragma unroll
  for (int i = 0; i < 4; ++i) {
    int r = tr + i * 8;
    tile[r][tc] = ine[(size_t)(r0 + r) * C + (c0 + tc)];
  }
  __syncthreads();
#pragma unroll
  for (int i = 0; i < 4; ++i) {
    int r = tr + i * 8;
    oute[(size_t)(c0 + r) * R + (r0 + tc)] = f2bf(tile[tc][r]);
  }
}

// ---------------- gating (+ fused x->bf16), 8-way d-split, block-aggregated atomics ----------------
__global__ __launch_bounds__(256) void k_gate(const float* __restrict__ x,
                                              const float* __restrict__ Wg,
                                              const float* __restrict__ bg,
                                              float* __restrict__ topi,
                                              unsigned short* __restrict__ xbf,
                                              int* __restrict__ pairTok,
                                              int* __restrict__ tokEP,
                                              float* __restrict__ tokW,
                                              int* __restrict__ cnt) {
  __shared__ float wgs[DIM * NE + 28];    // sw(i) = i + (i>>9)*4
  __shared__ double partial[32][8][9];    // padded
  __shared__ double bgs[NE];
  __shared__ int lcnt[NE], lbase[NE];
  int t = threadIdx.x;
  if (t < NE) { bgs[t] = (double)bg[t]; lcnt[t] = 0; }
  for (int i = t; i < DIM * NE; i += 256) wgs[i + ((i >> 9) << 2)] = Wg[i];
  __syncthreads();

  int tokLocal = t >> 3;                  // 0..31
  int part = t & 7;                       // 0..7
  int token = blockIdx.x * 32 + tokLocal;
  size_t xoff = (size_t)token * DIM + part * 64;
  const float4* xr = (const float4*)(x + xoff);
  ushort4* xw = (ushort4*)(xbf + xoff);

  double acc[NE];
#pragma unroll
  for (int e = 0; e < NE; ++e) acc[e] = 0.0;

#pragma unroll
  for (int j = 0; j < 16; ++j) {          // 16 x float4 = 64 d
    float4 xv4 = xr[j];
    ushort4 o;
    o.x = f2bf(xv4.x); o.y = f2bf(xv4.y); o.z = f2bf(xv4.z); o.w = f2bf(xv4.w);
    xw[j] = o;
    const float* wb = &wgs[part * 516 + (j * 4) * 8];
#pragma unroll
    for (int k = 0; k < 4; ++k) {
      double xv = (double)((const float*)&xv4)[k];
#pragma unroll
      for (int e = 0; e < NE; ++e) acc[e] += xv * (double)wb[k * 8 + e];
    }
  }

#pragma unroll
  for (int e = 0; e < NE; ++e) partial[tokLocal][part][e] = acc[e];
  __syncthreads();

  int i0 = 0, i1 = 0, ls0 = 0, ls1 = 0;
  float w0 = 0.f, w1 = 0.f;
  if (part == 0) {
    double lg[NE];
#pragma unroll
    for (int e = 0; e < NE; ++e) {
      double s = bgs[e];
#pragma unroll
      for (int p = 0; p < 8; ++p) s += partial[tokLocal][p][e];
      lg[e] = s;
    }
    for (int e = 1; e < NE; ++e) if (lg[e] > lg[i0]) i0 = e;
    i1 = (i0 == 0) ? 1 : 0;
    for (int e = i1 + 1; e < NE; ++e) if (e != i0 && lg[e] > lg[i1]) i1 = e;
    double ex = exp(lg[i1] - lg[i0]);
    w0 = (float)(1.0 / (1.0 + ex));
    w1 = (float)(ex / (1.0 + ex));
    topi[token * 2 + 0] = (float)i0;
    topi[token * 2 + 1] = (float)i1;
    ls0 = atomicAdd(&lcnt[i0], 1);        // LDS atomics: 32 threads, cheap
    ls1 = atomicAdd(&lcnt[i1], 1);
  }
  __syncthreads();
  if (t < NE) lbase[t] = atomicAdd(&cnt[t], lcnt[t]);   // 8 global atomics/block
  __syncthreads();
  if (part == 0) {
    int s0 = lbase[i0] + ls0;
    int s1 = lbase[i1] + ls1;
    pairTok[i0 * B_TOK + s0] = token;
    pairTok[i1 * B_TOK + s1] = token;
    tokEP[token * 2 + 0] = (i0 << 16) | s0;  tokW[token * 2 + 0] = w0;
    tokEP[token * 2 + 1] = (i1 << 16) | s1;  tokW[token * 2 + 1] = w1;
  }
}

// ---------------- schedule ----------------
__global__ __launch_bounds__(256) void k_schedule(const int* __restrict__ cnt,
                                                  int* __restrict__ numTiles,
                                                  int4* __restrict__ tileInfo64,
                                                  int* __restrict__ sBase,
                                                  int* __restrict__ pairTok) {
  __shared__ int sc[NE], spc[NE];
  int t = threadIdx.x;
  if (t == 0) {
    int off = 0, nt64 = 0;
    for (int e = 0; e < NE; ++e) {
      int c = cnt[e];
      sc[e] = c;
      int tl = (c + 127) >> 7;
      spc[e] = tl << 7;
      sBase[e] = off;
      for (int lt = 0; lt < tl * 2; ++lt)
        tileInfo64[nt64++] = make_int4(e, e * B_TOK + lt * 64, off + lt * 64, 0);
      off += tl << 7;
    }
    numTiles[1] = nt64;
  }
  __syncthreads();
  for (int e = 0; e < NE; ++e)
    for (int i = sc[e] + t; i < spc[e]; i += 256)
      pairTok[e * B_TOK + i] = 0;
}

// ---------------- GEMM1: h = gelu(gather(x) @ W1[e] + b1[e]) -> bf16
//  64x64 tile, BK=64 (8 K-steps), XOR-swizzled LDS, 2-buf dbuf, 256 thr / 4 waves,
//  XCD swizzle, swapped-MFMA epilogue. (gemm2's proven structure, ported)
__global__ __launch_bounds__(256) void k_gemm1(const unsigned short* __restrict__ xbf,
                                               const unsigned short* __restrict__ w1t,
                                               const float* __restrict__ b1,
                                               const int4* __restrict__ tileInfo64,
                                               const int* __restrict__ numTiles,
                                               const int* __restrict__ pairTok,
                                               unsigned short* __restrict__ hbuf) {
  // 8704 blocks = 8 xcd x (34 tiles x 32 n-blocks of 64 cols)
  int L = blockIdx.y * 32 + blockIdx.x;
  int xcd = L & 7, o = L >> 3;
  int tile = xcd * 34 + (o >> 5);
  int n0 = (o & 31) * 64;
  if (tile >= numTiles[1]) return;
  int4 info = tileInfo64[tile];
  int e = info.x, pairBase = info.y, slotBase = info.z;
  __shared__ unsigned short As[2][4096];   // [row<64][granule<8][8], granule pre-swizzled by row&7
  __shared__ unsigned short Bs[2][4096];
  __shared__ int toks[64];
  int t = threadIdx.x;
  if (t < 64) toks[t] = pairTok[pairBase + t];
  __syncthreads();
  int wv = t >> 6, lane = t & 63;

  int sg = t & 7, srow = t >> 3;
  int sj = sg ^ (srow & 7);
  const unsigned short* aSrc0 = xbf + (size_t)toks[srow] * DIM + sj * 8;
  const unsigned short* aSrc1 = xbf + (size_t)toks[srow + 32] * DIM + sj * 8;
  const unsigned short* bSrc0 = w1t + ((size_t)e * HID + n0 + srow) * DIM + sj * 8;
  const unsigned short* bSrc1 = w1t + ((size_t)e * HID + n0 + srow + 32) * DIM + sj * 8;

  int g16 = lane >> 4, r16 = lane & 15;
  int wr = (wv >> 1) * 32, wc = (wv & 1) * 32;
  f32x4 acc[2][2];
#pragma unroll
  for (int mi = 0; mi < 2; ++mi)
#pragma unroll
    for (int ni = 0; ni < 2; ++ni) acc[mi][ni] = (f32x4){0.f, 0.f, 0.f, 0.f};

  gld_lds16(aSrc0, &As[0][wv * 512]);
  gld_lds16(aSrc1, &As[0][2048 + wv * 512]);
  gld_lds16(bSrc0, &Bs[0][wv * 512]);
  gld_lds16(bSrc1, &Bs[0][2048 + wv * 512]);
  __syncthreads();

  for (int ks = 0; ks < 8; ++ks) {         // K = 512, BK = 64
    int cur = ks & 1;
    if (ks < 7) {
      int nb = cur ^ 1;
      int k0n = (ks + 1) * 64;
      gld_lds16(aSrc0 + k0n, &As[nb][wv * 512]);
      gld_lds16(aSrc1 + k0n, &As[nb][2048 + wv * 512]);
      gld_lds16(bSrc0 + k0n, &Bs[nb][wv * 512]);
      gld_lds16(bSrc1 + k0n, &Bs[nb][2048 + wv * 512]);
    }
    short8 am[2][2], bn[2][2];
#pragma unroll
    for (int mi = 0; mi < 2; ++mi) {
      int rrow = wr + mi * 16 + r16;
#pragma unroll
      for (int kk = 0; kk < 2; ++kk) {
        int j = (kk * 4 + g16) ^ (rrow & 7);
        am[mi][kk] = *(const short8*)&As[cur][rrow * 64 + j * 8];
      }
    }
#pragma unroll
    for (int ni = 0; ni < 2; ++ni) {
      int rrow = wc + ni * 16 + r16;
#pragma unroll
      for (int kk = 0; kk < 2; ++kk) {
        int j = (kk * 4 + g16) ^ (rrow & 7);
        bn[ni][kk] = *(const short8*)&Bs[cur][rrow * 64 + j * 8];
      }
    }
    // swapped operands: lane holds slot row (r16) x 4 consecutive cols (g16*4+r)
#pragma unroll
    for (int mi = 0; mi < 2; ++mi)
#pragma unroll
      for (int ni = 0; ni < 2; ++ni)
#pragma unroll
        for (int kk = 0; kk < 2; ++kk)
          acc[mi][ni] = __builtin_amdgcn_mfma_f32_16x16x32_bf16(bn[ni][kk], am[mi][kk], acc[mi][ni], 0, 0, 0);
    __syncthreads();
  }

#pragma unroll
  for (int mi = 0; mi < 2; ++mi) {
    int srow2 = wr + mi * 16 + r16;
    size_t base = (size_t)(slotBase + srow2) * HID;
#pragma unroll
    for (int ni = 0; ni < 2; ++ni) {
      int col0 = n0 + wc + ni * 16 + g16 * 4;
      float4 b4 = *(const float4*)&b1[e * HID + col0];
      unsigned h0 = f2bf(gelu_fast(acc[mi][ni][0] + b4.x));
      unsigned h1 = f2bf(gelu_fast(acc[mi][ni][1] + b4.y));
      unsigned h2 = f2bf(gelu_fast(acc[mi][ni][2] + b4.z));
      unsigned h3 = f2bf(gelu_fast(acc[mi][ni][3] + b4.w));
      uint2 pk;
      pk.x = h0 | (h1 << 16);
      pk.y = h2 | (h3 << 16);
      *(uint2*)&hbuf[base + col0] = pk;
    }
  }
}

// ---------------- GEMM2: ybuf[slot] = h[slot] @ W2[e] + b2[e]
//  64x64x64, XOR-swizzled LDS, 2-phase dbuf, XCD swizzle, swapped-MFMA epilogue.
__global__ __launch_bounds__(256) void k_gemm2(const unsigned short* __restrict__ hbuf,
                                               const unsigned short* __restrict__ w2t,
                                               const float* __restrict__ b2,
                                               const int4* __restrict__ tileInfo64,
                                               const int* __restrict__ numTiles,
                                               unsigned short* __restrict__ ybuf) {
  // 2176 blocks = 8 xcd x (34 tiles x 8 n-blocks)
  int L = blockIdx.y * 8 + blockIdx.x;
  int xcd = L & 7, o = L >> 3;
  int tile = xcd * 34 + (o >> 3);
  int n0 = (o & 7) * 64;
  if (tile >= numTiles[1]) return;
  int4 info = tileInfo64[tile];
  int e = info.x, slotBase = info.z;
  __shared__ unsigned short As[2][4096];   // [row<64][granule<8][8], granule pre-swizzled by row&7
  __shared__ unsigned short Bs[2][4096];
  int t = threadIdx.x;
  int wv = t >> 6, lane = t & 63;

  int sg = t & 7, srow = t >> 3;
  int sj = sg ^ (srow & 7);
  const unsigned short* aSrc0 = hbuf + (size_t)(slotBase + srow) * HID + sj * 8;
  const unsigned short* aSrc1 = hbuf + (size_t)(slotBase + srow + 32) * HID + sj * 8;
  const unsigned short* bSrc0 = w2t + ((size_t)e * DIM + n0 + srow) * HID + sj * 8;
  const unsigned short* bSrc1 = w2t + ((size_t)e * DIM + n0 + srow + 32) * HID + sj * 8;

  int g16 = lane >> 4, r16 = lane & 15;
  int wr = (wv >> 1) * 32, wc = (wv & 1) * 32;
  f32x4 acc[2][2];
#pragma unroll
  for (int mi = 0; mi < 2; ++mi)
#pragma unroll
    for (int ni = 0; ni < 2; ++ni) acc[mi][ni] = (f32x4){0.f, 0.f, 0.f, 0.f};

  gld_lds16(aSrc0, &As[0][wv * 512]);
  gld_lds16(aSrc1, &As[0][2048 + wv * 512]);
  gld_lds16(bSrc0, &Bs[0][wv * 512]);
  gld_lds16(bSrc1, &Bs[0][2048 + wv * 512]);
  __syncthreads();

  for (int ks = 0; ks < 32; ++ks) {
    int cur = ks & 1;
    if (ks < 31) {
      int nb = cur ^ 1;
      int k0n = (ks + 1) * 64;
      gld_lds16(aSrc0 + k0n, &As[nb][wv * 512]);
      gld_lds16(aSrc1 + k0n, &As[nb][2048 + wv * 512]);
      gld_lds16(bSrc0 + k0n, &Bs[nb][wv * 512]);
      gld_lds16(bSrc1 + k0n, &Bs[nb][2048 + wv * 512]);
    }
    short8 am[2][2], bn[2][2];
#pragma unroll
    for (int mi = 0; mi < 2; ++mi) {
      int rrow = wr + mi * 16 + r16;
#pragma unroll
      for (int kk = 0; kk < 2; ++kk) {
        int j = (kk * 4 + g16) ^ (rrow & 7);
        am[mi][kk] = *(const short8*)&As[cur][rrow * 64 + j * 8];
      }
    }
#pragma unroll
    for (int ni = 0; ni < 2; ++ni) {
      int rrow = wc + ni * 16 + r16;
#pragma unroll
      for (int kk = 0; kk < 2; ++kk) {
        int j = (kk * 4 + g16) ^ (rrow & 7);
        bn[ni][kk] = *(const short8*)&Bs[cur][rrow * 64 + j * 8];
      }
    }
    // swapped operands: lane holds slot row (r16) x 4 consecutive cols (g16*4+r)
#pragma unroll
    for (int mi = 0; mi < 2; ++mi)
#pragma unroll
      for (int ni = 0; ni < 2; ++ni)
#pragma unroll
        for (int kk = 0; kk < 2; ++kk)
          acc[mi][ni] = __builtin_amdgcn_mfma_f32_16x16x32_bf16(bn[ni][kk], am[mi][kk], acc[mi][ni], 0, 0, 0);
    __syncthreads();
  }

#pragma unroll
  for (int mi = 0; mi < 2; ++mi) {
    int srow2 = wr + mi * 16 + r16;
    size_t base = (size_t)(slotBase + srow2) * DIM;
#pragma unroll
    for (int ni = 0; ni < 2; ++ni) {
      int col0 = n0 + wc + ni * 16 + g16 * 4;
      float4 b4 = *(const float4*)&b2[e * DIM + col0];
      unsigned y0 = f2bf(acc[mi][ni][0] + b4.x);
      unsigned y1 = f2bf(acc[mi][ni][1] + b4.y);
      unsigned y2 = f2bf(acc[mi][ni][2] + b4.z);
      unsigned y3 = f2bf(acc[mi][ni][3] + b4.w);
      uint2 pk;
      pk.x = y0 | (y1 << 16);
      pk.y = y2 | (y3 << 16);
      *(uint2*)&ybuf[base + col0] = pk;
    }
  }
}

// ---------------- combine: out[token] = w0*y[slot0] + w1*y[slot1] ----------------
__global__ __launch_bounds__(256) void k_combine(const unsigned short* __restrict__ ybuf,
                                                 const int* __restrict__ tokEP,
                                                 const float* __restrict__ tokW,
                                                 const int* __restrict__ sBase,
                                                 float* __restrict__ out) {
  int gid = blockIdx.x * 256 + threadIdx.x;   // B_TOK*DIM/4 threads
  int token = gid >> 7;
  int c4 = (gid & 127) * 4;
  int ep0 = tokEP[token * 2], ep1 = tokEP[token * 2 + 1];
  float w0 = tokW[token * 2], w1 = tokW[token * 2 + 1];
  size_t s0 = (size_t)(sBase[ep0 >> 16] + (ep0 & 0xFFFF));
  size_t s1 = (size_t)(sBase[ep1 >> 16] + (ep1 & 0xFFFF));
  ushort4 a = *(const ushort4*)&ybuf[s0 * DIM + c4];
  ushort4 b = *(const ushort4*)&ybuf[s1 * DIM + c4];
  float4 o;
  o.x = w0 * bf2f(a.x) + w1 * bf2f(b.x);
  o.y = w0 * bf2f(a.y) + w1 * bf2f(b.y);
  o.z = w0 * bf2f(a.z) + w1 * bf2f(b.z);
  o.w = w0 * bf2f(a.w) + w1 * bf2f(b.w);
  ((float4*)out)[gid] = o;
}

extern "C" void kernel_launch(void* const* d_in, const int* in_sizes, int n_in,
                              void* d_out, int out_size, void* d_ws, size_t ws_size,
                              hipStream_t stream) {
  (void)in_sizes; (void)n_in; (void)out_size; (void)ws_size;
  const float* x  = (const float*)d_in[0];
  const float* Wg = (const float*)d_in[1];
  const float* bg = (const float*)d_in[2];
  const float* W1 = (const float*)d_in[3];
  const float* b1 = (const float*)d_in[4];
  const float* W2 = (const float*)d_in[5];
  const float* b2 = (const float*)d_in[6];
  float* out  = (float*)d_out;
  float* topi = out + (size_t)B_TOK * DIM;

  char* ws = (char*)d_ws;
  int*  cnt        = (int*)(ws + 0);                  // 32 B
  int*  numTiles   = (int*)(ws + 64);                 // 2 ints
  int*  sBase      = (int*)(ws + 128);                // 8 ints
  int4* tileInfo64 = (int4*)(ws + 256);               // 272*16 B
  int*  pairTok    = (int*)(ws + 16384);              // 256 KiB
  int*  tokEP      = (int*)(ws + 16384 + 262144);     // 64 KiB
  float* tokW      = (float*)(ws + 16384 + 262144 + 65536); // 64 KiB
  unsigned short* ybuf = (unsigned short*)(ws + (1u << 20));  // 17.8 MiB, overlays xbf+w1t (dead after gemm1)
  unsigned short* xbf  = (unsigned short*)(ws + (1u << 20));
  unsigned short* w1t  = (unsigned short*)(ws + (1u << 20) + 8388608);
  unsigned short* w2t  = (unsigned short*)(ws + (1u << 20) + 8388608 + 16777216);
  unsigned short* hbuf = (unsigned short*)(ws + (1u << 20) + 8388608 + 16777216 + 16777216);

  hipMemsetAsync(cnt, 0, 64, stream);

  k_transpose2<<<dim3(1024, 1, 16), 256, 0, stream>>>(W1, W2, w1t, w2t);
  k_gate<<<dim3(B_TOK / 32), 256, 0, stream>>>(x, Wg, bg, topi, xbf, pairTok, tokEP, tokW, cnt);
  k_schedule<<<dim3(1), 256, 0, stream>>>(cnt, numTiles, tileInfo64, sBase, pairTok);
  k_gemm1<<<dim3(32, MAX_TILES64), 256, 0, stream>>>(xbf, w1t, b1, tileInfo64, numTiles, pairTok, hbuf);
  k_gemm2<<<dim3(8, MAX_TILES64), 256, 0, stream>>>(hbuf, w2t, b2, tileInfo64, numTiles, ybuf);
  k_combine<<<dim3((B_TOK * DIM) / 1024), 256, 0, stream>>>(ybuf, tokEP, tokW, sBase, out);
}